// Round 1
// baseline (282.431 us; speedup 1.0000x reference)
//
#include <hip/hip_runtime.h>

// quadLayer: B=8, H=W=64, C=16, K=S=2, FM=32 -> oh=ow=32, 8192 locations,
// 8192 fp32 outputs per location (268 MB total). Structural floor = output
// write stream (~43 us at 6.3 TB/s).
//
// out[loc*8192 + c*512 + a*32 + f] =
//   sum_m p[a,m]*W1[c*128 + m*32 + f] + sum_q so[a,q]*W2[c*512 + q*32 + f]
// with so[a, m1*4+m2] = p[a,m1]*p[a,m2]. Factored form (exact same FLOP count,
// no materialized so):
//   t_m = W1[c,m,:] + sum_m2 p[a,m2] * W2[c, m*4+m2, :]
//   out = sum_m p[a,m] * t_m
//
// Patch depth d = a*4+m maps to x[b, 2h+ki, 2w+kj, c16] with d=(ki*2+kj)*16+c16.
// A thread owning a in [8*half, 8*half+8) needs d in [32*half, 32*half+32) =
// 32 CONTIGUOUS floats of x (row 2h+half, cols 2w..2w+1, all 16 channels) --
// wave-uniform address, one broadcast L1 transaction. No LDS, no barriers:
// nontemporal stores stream without any vmcnt(0) drain.

typedef float f4 __attribute__((ext_vector_type(4)));

#define LPB 4  // locations per block; 8192/4 = 2048 blocks

__global__ __launch_bounds__(256, 3) void quad_kernel(
    const float* __restrict__ x,
    const float* __restrict__ W1,
    const float* __restrict__ W2,
    float* __restrict__ out)
{
    const int t     = threadIdx.x;
    const int f4off = (t & 7) * 4;     // f in {0,4,...,28}
    const int s     = t >> 3;          // 0..31
    const int c     = s & 15;          // output channel c
    const int half  = s >> 4;          // a-range: [8*half, 8*half+8), wave-uniform

    // --- weights to registers: 20 float4 = 80 VGPRs, L1/L2-resident loads ---
    f4 w1r[4];
    f4 w2r[16];
    {
        const float* W1p = W1 + c * 128 + f4off;
#pragma unroll
        for (int m = 0; m < 4; ++m)
            w1r[m] = *(const f4*)(W1p + m * 32);
        const float* W2p = W2 + c * 512 + f4off;
#pragma unroll
        for (int q = 0; q < 16; ++q)
            w2r[q] = *(const f4*)(W2p + q * 32);
    }

    const int loc0 = blockIdx.x * LPB;

    for (int i = 0; i < LPB; ++i) {
        const int loc = loc0 + i;
        const int b  = loc >> 10;         // /1024
        const int hw = loc & 1023;
        const int h  = hw >> 5;
        const int w  = hw & 31;

        // 32 contiguous floats: x[b][2h+half][2w..2w+1][0:16]
        // (wave-uniform address -> broadcast load, L1-resident 4 MB input)
        const float* src =
            x + (((b * 64 + 2 * h + half) * 64) + 2 * w) * 16;
        f4 pv[8];
#pragma unroll
        for (int j = 0; j < 8; ++j)
            pv[j] = *(const f4*)(src + j * 4);

        float* outp = out + (size_t)loc * 8192 + c * 512 + half * 256 + f4off;

#pragma unroll
        for (int j = 0; j < 8; ++j) {
            const f4 P = pv[j];   // p[a, 0..3] for a = 8*half + j

            // t_m = W1[m] + sum_m2 P[m2] * W2[m*4+m2]  (4 independent chains)
            f4 t0 = w1r[0];
            f4 t1 = w1r[1];
            f4 t2 = w1r[2];
            f4 t3 = w1r[3];
            t0 += P.x * w2r[0];
            t1 += P.x * w2r[4];
            t2 += P.x * w2r[8];
            t3 += P.x * w2r[12];
            t0 += P.y * w2r[1];
            t1 += P.y * w2r[5];
            t2 += P.y * w2r[9];
            t3 += P.y * w2r[13];
            t0 += P.z * w2r[2];
            t1 += P.z * w2r[6];
            t2 += P.z * w2r[10];
            t3 += P.z * w2r[14];
            t0 += P.w * w2r[3];
            t1 += P.w * w2r[7];
            t2 += P.w * w2r[11];
            t3 += P.w * w2r[15];

            // out = sum_m P[m] * t_m
            f4 acc = P.x * t0;
            acc += P.y * t1;
            acc += P.z * t2;
            acc += P.w * t3;

            __builtin_nontemporal_store(acc, (f4*)(outp + j * 32));
        }
    }
}

extern "C" void kernel_launch(void* const* d_in, const int* in_sizes, int n_in,
                              void* d_out, int out_size, void* d_ws, size_t ws_size,
                              hipStream_t stream) {
    const float* x  = (const float*)d_in[0];   // [8,64,64,16]
    const float* W1 = (const float*)d_in[1];   // [16,4,32]
    const float* W2 = (const float*)d_in[2];   // [16,16,32]
    float* out = (float*)d_out;                // [8,32,32,8192]

    const int n_loc = 8 * 32 * 32;             // 8192
    dim3 grid(n_loc / LPB), block(256);
    quad_kernel<<<grid, block, 0, stream>>>(x, W1, W2, out);
}

// Round 4
// 273.712 us; speedup vs baseline: 1.0319x; 1.0319x over previous
//
#include <hip/hip_runtime.h>

// quadLayer: B=8, H=W=64, C=16, K=S=2, FM=32 -> oh=ow=32, 8192 locations,
// 8192 fp32 outputs per location (268 MB total). Output-write-bound.
//
// out[loc*8192 + c*512 + a*32 + f] =
//   sum_m p[a,m]*W1[c,m,f] + sum_{m1,m2} p[a,m1]p[a,m2]*W2[c,m1*4+m2,f]
// Factored (same FLOPs, no materialized outer product):
//   t_m = W1[c,m,:] + sum_m2 p[a,m2]*W2[c,m*4+m2,:];  out = sum_m p[a,m]*t_m
//
// Store-stream design: every wave store instruction writes one ALIGNED,
// CONTIGUOUS 1-KB segment (lane*16 B), ascending addresses -- identical in
// shape to the 6.4 TB/s fillBufferAligned stream on this same buffer.
// That forces c to be wave-uniform per store: lane -> (a_low = lane>>3,
// f4 = lane&7); wave w owns c in [4w, 4w+4) via a runtime c-loop.
// Weights (40 KB total) are L1-resident: each c-iteration loads that c's
// 20 float4 directly from global (8-way lane-replicated addresses, L1 hits).
// No LDS, no barriers, no launch-bounds forcing -- minimal failure surface.

typedef float f4 __attribute__((ext_vector_type(4)));

#define LPB 4  // locations per block; 8192/4 = 2048 blocks

__global__ __launch_bounds__(256) void quad_kernel(
    const float* __restrict__ x,
    const float* __restrict__ W1,
    const float* __restrict__ W2,
    float* __restrict__ out)
{
    const int t     = threadIdx.x;
    const int w     = t >> 6;          // wave 0..3 -> c in [4w, 4w+4)
    const int lane  = t & 63;
    const int A     = lane >> 3;       // a_low 0..7 (thread covers a=A, A+8)
    const int f4off = (lane & 7) * 4;  // f in {0,4,...,28}

    const int loc0 = blockIdx.x * LPB;

    // Patch registers for all LPB locations: p[A,0..3] and p[A+8,0..3] are
    // contiguous f4s of x (depth d=a*4+m maps to x[b,2h+ki,2w+kj,c16] with
    // d=(ki*2+kj)*16+c16, so d in [A*4, A*4+4) is 16 contiguous bytes).
    f4 P0[LPB], P1[LPB];
#pragma unroll
    for (int li = 0; li < LPB; ++li) {
        const int loc = loc0 + li;
        const int b  = loc >> 10;
        const int hw = loc & 1023;
        const int h  = hw >> 5;
        const int ww = hw & 31;
        const float* row0 = x + (((b * 64 + 2 * h) * 64) + 2 * ww) * 16;
        P0[li] = *(const f4*)(row0 + A * 4);            // ki=0 row: a = A
        P1[li] = *(const f4*)(row0 + 64 * 16 + A * 4);  // ki=1 row: a = A+8
    }

    float* const outb = out + (size_t)loc0 * 8192 + lane * 4;

#pragma unroll 1  // runtime c-loop: one 80-VGPR weight set live at a time
    for (int cidx = 0; cidx < 4; ++cidx) {
        const int c = w * 4 + cidx;

        // This c's weights: 20 f4 per thread, L1-resident (40 KB total).
        const float* W1p = W1 + c * 128 + f4off;
        const float* W2p = W2 + c * 512 + f4off;
        f4 w1r[4], w2r[16];
#pragma unroll
        for (int q = 0; q < 4; ++q)  w1r[q] = *(const f4*)(W1p + q * 32);
#pragma unroll
        for (int q = 0; q < 16; ++q) w2r[q] = *(const f4*)(W2p + q * 32);

        float* const outc = outb + c * 512;

#pragma unroll
        for (int li = 0; li < LPB; ++li) {
#pragma unroll
            for (int half = 0; half < 2; ++half) {
                const f4 P = half ? P1[li] : P0[li];  // p[a,:], a=A+8*half

                f4 t0 = w1r[0], t1 = w1r[1], t2 = w1r[2], t3 = w1r[3];
                t0 += P.x * w2r[0];  t1 += P.x * w2r[4];
                t2 += P.x * w2r[8];  t3 += P.x * w2r[12];
                t0 += P.y * w2r[1];  t1 += P.y * w2r[5];
                t2 += P.y * w2r[9];  t3 += P.y * w2r[13];
                t0 += P.z * w2r[2];  t1 += P.z * w2r[6];
                t2 += P.z * w2r[10]; t3 += P.z * w2r[14];
                t0 += P.w * w2r[3];  t1 += P.w * w2r[7];
                t2 += P.w * w2r[11]; t3 += P.w * w2r[15];

                f4 acc = P.x * t0;
                acc += P.y * t1;
                acc += P.z * t2;
                acc += P.w * t3;

                // wave store = 64 lanes x 16 B = one contiguous aligned 1 KB
                *(f4*)(outc + (size_t)li * 8192 + half * 256) = acc;
            }
        }
    }
}

extern "C" void kernel_launch(void* const* d_in, const int* in_sizes, int n_in,
                              void* d_out, int out_size, void* d_ws, size_t ws_size,
                              hipStream_t stream) {
    const float* x  = (const float*)d_in[0];   // [8,64,64,16]
    const float* W1 = (const float*)d_in[1];   // [16,4,32]
    const float* W2 = (const float*)d_in[2];   // [16,16,32]
    float* out = (float*)d_out;                // [8,32,32,8192]

    const int n_loc = 8 * 32 * 32;             // 8192
    dim3 grid(n_loc / LPB), block(256);
    quad_kernel<<<grid, block, 0, stream>>>(x, W1, W2, out);
}